// Round 3
// baseline (259.770 us; speedup 1.0000x reference)
//
#include <hip/hip_runtime.h>
#include <math.h>

// LayerNorm(Re(FFT(x, axis=-1))), x: (B=4, N=4096, C=2048) fp32.
// One 256-thread block per PAIR of rows: z = x_even + i*x_odd.
// Register-resident Stockham FFT: radix-8 stages (S=1,8,64) + final radix-4
// (S=512, twiddle-free, in registers). LDS only for the 3 inter-stage
// transposes. Conjugate-symmetry untangle via __shfl_xor(.,1) (partner pairs
// {s, 256-s} lane-adjacent). Twiddles come from a 16 KB L2-hot device-global
// table (init kernel in the same graph) instead of per-thread sincos+power
// chains. Output uses nontemporal stores so the 134 MB write stream does not
// evict the (L3-resident) input.
// Padded LDS phys(i) = i + (i>>3): 18.4 KB/block -> 8 blocks/CU.

#define TPB 256
#define CD  2048

// Twiddle table (float2), 2044 used entries:
// [0,1792):     stage A, idx=(r-1)*256+p, W_2048^(p*r), p in [0,256), r in [1,8)
// [1792,2016):  stage B, idx=1792+(r-1)*32+p, W_256^(p*r), p in [0,32)
// [2016,2044):  stage C, idx=2016+(r-1)*4+p,  W_32^(p*r),  p in [0,4)
__device__ float2 g_tw[2048];

__global__ void twiddle_init_kernel()
{
    const int gid = blockIdx.x * blockDim.x + threadIdx.x;   // 2048 threads
    int r, p, N_;
    if (gid < 1792)      { r = 1 + gid / 256;              p = gid & 255; N_ = 2048; }
    else if (gid < 2016) { int e = gid - 1792; r = 1 + e / 32; p = e & 31; N_ = 256; }
    else if (gid < 2044) { int e = gid - 2016; r = 1 + e / 4;  p = e & 3;  N_ = 32; }
    else return;
    const double th = -6.28318530717958647692 * (double)(p * r) / (double)N_;
    g_tw[gid] = make_float2((float)cos(th), (float)sin(th));
}

__device__ __forceinline__ float2 cadd(float2 a, float2 b){ return make_float2(a.x+b.x, a.y+b.y); }
__device__ __forceinline__ float2 csub(float2 a, float2 b){ return make_float2(a.x-b.x, a.y-b.y); }

// y_r = sum_k z_k * exp(-2*pi*i*k*r/8), natural output order.
__device__ __forceinline__ void dft8(const float2* z, float2* y)
{
    const float C8 = 0.70710678118654752440f;  // sqrt(2)/2
    float2 a0=cadd(z[0],z[4]), a1=cadd(z[1],z[5]), a2=cadd(z[2],z[6]), a3=cadd(z[3],z[7]);
    float2 b0=csub(z[0],z[4]), b1=csub(z[1],z[5]), b2=csub(z[2],z[6]), b3=csub(z[3],z[7]);
    float2 t1=make_float2(C8*(b1.x+b1.y), C8*(b1.y-b1.x));     // b1 * w8^1
    float2 t2=make_float2(b2.y, -b2.x);                        // b2 * w8^2 = -i
    float2 t3=make_float2(C8*(b3.y-b3.x), -C8*(b3.x+b3.y));    // b3 * w8^3
    {   // even outputs = DFT4(a0..a3)
        float pr=a0.x+a2.x, pi=a0.y+a2.y, mr=a0.x-a2.x, mi=a0.y-a2.y;
        float qr=a1.x+a3.x, qi=a1.y+a3.y, nr=a1.x-a3.x, ni=a1.y-a3.y;
        y[0]=make_float2(pr+qr,pi+qi); y[2]=make_float2(mr+ni,mi-nr);
        y[4]=make_float2(pr-qr,pi-qi); y[6]=make_float2(mr-ni,mi+nr);
    }
    {   // odd outputs = DFT4(b0,t1,t2,t3)
        float pr=b0.x+t2.x, pi=b0.y+t2.y, mr=b0.x-t2.x, mi=b0.y-t2.y;
        float qr=t1.x+t3.x, qi=t1.y+t3.y, nr=t1.x-t3.x, ni=t1.y-t3.y;
        y[1]=make_float2(pr+qr,pi+qi); y[3]=make_float2(mr+ni,mi-nr);
        y[5]=make_float2(pr-qr,pi-qi); y[7]=make_float2(mr-ni,mi+nr);
    }
}

// Stockham store with preloaded twiddles w[r-1] = W^(p*r).
template<int OFFM>
__device__ __forceinline__ void r8_store_tw(float2* Lw, const float2* y, const float2* w)
{
    Lw[0] = y[0];
#pragma unroll
    for (int r = 1; r < 8; ++r)
        Lw[OFFM*r] = make_float2(w[r-1].x*y[r].x - w[r-1].y*y[r].y,
                                 w[r-1].x*y[r].y + w[r-1].y*y[r].x);
}

__global__ __launch_bounds__(TPB, 8) void fourier_ln_kernel(
    const float* __restrict__ x,
    const float* __restrict__ gamma,
    const float* __restrict__ beta,
    float* __restrict__ out)
{
    __shared__ float2 L[2304];    // 2048 logical + pad: phys(i) = i + (i>>3)
    __shared__ float rmem[16];    // cross-wave reduction scratch

    const int t  = threadIdx.x;
    const int t8 = t >> 3;
    const long long row0 = 2LL * (long long)blockIdx.x;
    const float* __restrict__ x0 = x + row0 * CD;
    const float* __restrict__ x1 = x0 + CD;

    // Direct strided-coalesced loads: element t+256r of z = x0 + i*x1.
    float2 z[8], y[8];
#pragma unroll
    for (int r = 0; r < 8; ++r) {
        const int k = t + 256*r;
        z[r] = make_float2(x0[k], x1[k]);
    }
    // Stage-A twiddles (coalesced, L2-hot), issued while x loads are in flight.
    float2 wA[7];
#pragma unroll
    for (int r = 0; r < 7; ++r) wA[r] = g_tw[r*256 + t];

    float2* const Lr = L + (t + t8);   // logical t+256r -> phys base + 288r

    // Stage A: radix-8, S=1 (q=0, p=t). logical 8t+r -> phys 9t+r.
    dft8(z, y);
    r8_store_tw<1>(L + 9*t, y, wA);
    // Stage-B twiddles (8-lane broadcast): issue now, consume after barrier+read.
    float2 wB[7];
#pragma unroll
    for (int r = 0; r < 7; ++r) wB[r] = g_tw[1792 + r*32 + t8];
    __syncthreads();
#pragma unroll
    for (int r = 0; r < 8; ++r) z[r] = Lr[288*r];
    __syncthreads();

    // Stage B: radix-8, S=8 (q=t&7, p=t>>3). logical q+64p+8r -> phys q+72p+9r.
    dft8(z, y);
    r8_store_tw<9>(L + ((t & 7) + 72*t8), y, wB);
    // Stage-C twiddles (wave-uniform p = t>>6).
    float2 wC[7];
#pragma unroll
    for (int r = 0; r < 7; ++r) wC[r] = g_tw[2016 + r*4 + (t >> 6)];
    __syncthreads();
#pragma unroll
    for (int r = 0; r < 8; ++r) z[r] = Lr[288*r];
    __syncthreads();

    // Stage C: radix-8, S=64 (q=t&63, p=t>>6). logical q+512p+64r -> phys q+(q>>3)+576p+72r.
    dft8(z, y);
    {
        const int q = t & 63, p = t >> 6;
        r8_store_tw<72>(L + (q + (q >> 3) + 576*p), y, wC);
    }
    __syncthreads();

    // sigma: final-stage butterfly assignment. Even lane of a pair takes
    // sigma=u (u = t>>1 in [0,128)), odd lane takes 256-u (u==0 -> 128).
    // Partner pairs {sigma, 256-sigma} are lane-adjacent -> shfl_xor(1).
    const int u   = t >> 1;
    const int sig = (t & 1) ? ((u == 0) ? 128 : 256 - u) : u;

    // Stage C -> D read at butterfly sig: logical sig+256r.
    {
        const float2* Lsig = L + (sig + (sig >> 3));
#pragma unroll
        for (int r = 0; r < 8; ++r) z[r] = Lsig[288*r];
    }
    // (no further writes to L: no closing barrier needed)

    // Prefetch gamma/beta (L2-resident) under the stage-D VALU work.
    float gv[8], bv[8];
#pragma unroll
    for (int j = 0; j < 8; ++j) {
        gv[j] = gamma[sig + 256*j];
        bv[j] = beta[sig + 256*j];
    }

    // Stage D: radix-4, S=512, p=0 (twiddle-free), in registers.
    // Z[j] = FFT(row0 + i*row1) at k = sig + 256*j, natural order.
    float2 Z[8];
    {
        float pr=z[0].x+z[4].x, pi=z[0].y+z[4].y, mr=z[0].x-z[4].x, mi=z[0].y-z[4].y;
        float qr=z[2].x+z[6].x, qi=z[2].y+z[6].y, nr=z[2].x-z[6].x, ni=z[2].y-z[6].y;
        Z[0]=make_float2(pr+qr,pi+qi); Z[2]=make_float2(mr+ni,mi-nr);
        Z[4]=make_float2(pr-qr,pi-qi); Z[6]=make_float2(mr-ni,mi+nr);
    }
    {
        float pr=z[1].x+z[5].x, pi=z[1].y+z[5].y, mr=z[1].x-z[5].x, mi=z[1].y-z[5].y;
        float qr=z[3].x+z[7].x, qi=z[3].y+z[7].y, nr=z[3].x-z[7].x, ni=z[3].y-z[7].y;
        Z[1]=make_float2(pr+qr,pi+qi); Z[3]=make_float2(mr+ni,mi-nr);
        Z[5]=make_float2(pr-qr,pi-qi); Z[7]=make_float2(mr-ni,mi+nr);
    }

    // Untangle via lane-pair swap: Z[2048-k] lives at (partner lane, j'=7-j).
    // Specials: t==0 (sig=0) self-partner j'=(8-j)&7; t==1 (sig=128) j'=7-j.
    // Re X0[k] = (ReZ[k]+ReZ[-k])/2, Re X1[k] = (ImZ[k]+ImZ[-k])/2.
    float y0v[8], y1v[8];
    float s0=0.f, ss0=0.f, s1=0.f, ss1=0.f;
#pragma unroll
    for (int j = 0; j < 8; ++j) {
        float vx = __shfl_xor(Z[7-j].x, 1, 64);
        float vy = __shfl_xor(Z[7-j].y, 1, 64);
        const int ja = (8-j) & 7;                        // static per unrolled j
        float ax = (t == 0) ? Z[ja].x : Z[7-j].x;
        float ay = (t == 0) ? Z[ja].y : Z[7-j].y;
        vx = (t < 2) ? ax : vx;
        vy = (t < 2) ? ay : vy;
        float a = 0.5f*(Z[j].x + vx);
        float b = 0.5f*(Z[j].y + vy);
        y0v[j]=a; y1v[j]=b;
        s0+=a; ss0+=a*a; s1+=b; ss1+=b*b;
    }

    // Wave-64 shuffle reduce, then cross-wave partials via rmem; every
    // thread folds the 4 partials itself (no t==0 serialization/barrier).
#pragma unroll
    for (int off = 32; off > 0; off >>= 1) {
        s0  += __shfl_down(s0,  off, 64);
        ss0 += __shfl_down(ss0, off, 64);
        s1  += __shfl_down(s1,  off, 64);
        ss1 += __shfl_down(ss1, off, 64);
    }
    const int wave = t >> 6;
    if ((t & 63) == 0) {
        rmem[4*wave+0]=s0; rmem[4*wave+1]=ss0; rmem[4*wave+2]=s1; rmem[4*wave+3]=ss1;
    }
    __syncthreads();
    float S0=0.f, SS0=0.f, S1=0.f, SS1=0.f;
#pragma unroll
    for (int w = 0; w < 4; ++w) {
        S0+=rmem[4*w+0]; SS0+=rmem[4*w+1]; S1+=rmem[4*w+2]; SS1+=rmem[4*w+3];
    }
    const float inv = 1.0f/(float)CD;
    const float mu0 = S0*inv, mu1 = S1*inv;
    const float r0 = rsqrtf(SS0*inv - mu0*mu0 + 1e-5f);
    const float r1 = rsqrtf(SS1*inv - mu1*mu1 + 1e-5f);

    // Nontemporal stores: output is never read -> keep it out of L2/L3 so
    // the input stays L3-resident across graph replays.
    float* __restrict__ o0 = out + row0*CD;
    float* __restrict__ o1 = o0 + CD;
#pragma unroll
    for (int j = 0; j < 8; ++j) {
        const int k = sig + 256*j;
        const float rg0 = r0 * gv[j], rg1 = r1 * gv[j];
        __builtin_nontemporal_store((y0v[j] - mu0) * rg0 + bv[j], &o0[k]);
        __builtin_nontemporal_store((y1v[j] - mu1) * rg1 + bv[j], &o1[k]);
    }
}

extern "C" void kernel_launch(void* const* d_in, const int* in_sizes, int n_in,
                              void* d_out, int out_size, void* d_ws, size_t ws_size,
                              hipStream_t stream) {
    (void)in_sizes; (void)n_in; (void)d_ws; (void)ws_size; (void)out_size;
    const float* x     = (const float*)d_in[0];
    const float* gamma = (const float*)d_in[1];
    const float* beta  = (const float*)d_in[2];
    float* out = (float*)d_out;

    // Twiddle table init (16 KB device-global) — captured in the same graph,
    // negligible cost (8 blocks), keeps the main kernel free of sincos chains.
    twiddle_init_kernel<<<8, TPB, 0, stream>>>();

    const int total_rows = 4 * 4096;           // B * N
    const int blocks = total_rows / 2;         // one block per row pair
    fourier_ln_kernel<<<blocks, TPB, 0, stream>>>(x, gamma, beta, out);
}

// Round 6
// 257.752 us; speedup vs baseline: 1.0078x; 1.0078x over previous
//
#include <hip/hip_runtime.h>
#include <math.h>

// LayerNorm(Re(FFT(x, axis=-1))), x: (B=4, N=4096, C=2048) fp32.
// One 256-thread block per PAIR of rows: z = x_even + i*x_odd.
// Register-resident Stockham FFT: radix-8 stages (S=1,8,64) + final radix-4
// (S=512, twiddle-free, in registers). LDS only for the 3 inter-stage
// transposes. Conjugate-symmetry untangle via __shfl_xor(.,1) (partner pairs
// {s, 256-s} lane-adjacent). Twiddles from a 16 KB L2-hot device-global
// table (init kernel in the same graph) instead of per-thread sincos+power
// chains. Stores are PLAIN dword stores: the round-3 nontemporal experiment
// amplified HBM writes 139->163 MB and added ~27 us of stall -- reverted.
// Padded LDS phys(i) = i + (i>>3): 18.4 KB/block -> 8 blocks/CU.

#define TPB 256
#define CD  2048

// Twiddle table (float2), 2044 used entries:
// [0,1792):     stage A, idx=(r-1)*256+p, W_2048^(p*r), p in [0,256), r in [1,8)
// [1792,2016):  stage B, idx=1792+(r-1)*32+p, W_256^(p*r), p in [0,32)
// [2016,2044):  stage C, idx=2016+(r-1)*4+p,  W_32^(p*r),  p in [0,4)
__device__ float2 g_tw[2048];

__global__ void twiddle_init_kernel()
{
    const int gid = blockIdx.x * blockDim.x + threadIdx.x;   // 2048 threads
    int r, p, N_;
    if (gid < 1792)      { r = 1 + gid / 256;              p = gid & 255; N_ = 2048; }
    else if (gid < 2016) { int e = gid - 1792; r = 1 + e / 32; p = e & 31; N_ = 256; }
    else if (gid < 2044) { int e = gid - 2016; r = 1 + e / 4;  p = e & 3;  N_ = 32; }
    else return;
    const double th = -6.28318530717958647692 * (double)(p * r) / (double)N_;
    g_tw[gid] = make_float2((float)cos(th), (float)sin(th));
}

__device__ __forceinline__ float2 cadd(float2 a, float2 b){ return make_float2(a.x+b.x, a.y+b.y); }
__device__ __forceinline__ float2 csub(float2 a, float2 b){ return make_float2(a.x-b.x, a.y-b.y); }

// y_r = sum_k z_k * exp(-2*pi*i*k*r/8), natural output order.
__device__ __forceinline__ void dft8(const float2* z, float2* y)
{
    const float C8 = 0.70710678118654752440f;  // sqrt(2)/2
    float2 a0=cadd(z[0],z[4]), a1=cadd(z[1],z[5]), a2=cadd(z[2],z[6]), a3=cadd(z[3],z[7]);
    float2 b0=csub(z[0],z[4]), b1=csub(z[1],z[5]), b2=csub(z[2],z[6]), b3=csub(z[3],z[7]);
    float2 t1=make_float2(C8*(b1.x+b1.y), C8*(b1.y-b1.x));     // b1 * w8^1
    float2 t2=make_float2(b2.y, -b2.x);                        // b2 * w8^2 = -i
    float2 t3=make_float2(C8*(b3.y-b3.x), -C8*(b3.x+b3.y));    // b3 * w8^3
    {   // even outputs = DFT4(a0..a3)
        float pr=a0.x+a2.x, pi=a0.y+a2.y, mr=a0.x-a2.x, mi=a0.y-a2.y;
        float qr=a1.x+a3.x, qi=a1.y+a3.y, nr=a1.x-a3.x, ni=a1.y-a3.y;
        y[0]=make_float2(pr+qr,pi+qi); y[2]=make_float2(mr+ni,mi-nr);
        y[4]=make_float2(pr-qr,pi-qi); y[6]=make_float2(mr-ni,mi+nr);
    }
    {   // odd outputs = DFT4(b0,t1,t2,t3)
        float pr=b0.x+t2.x, pi=b0.y+t2.y, mr=b0.x-t2.x, mi=b0.y-t2.y;
        float qr=t1.x+t3.x, qi=t1.y+t3.y, nr=t1.x-t3.x, ni=t1.y-t3.y;
        y[1]=make_float2(pr+qr,pi+qi); y[3]=make_float2(mr+ni,mi-nr);
        y[5]=make_float2(pr-qr,pi-qi); y[7]=make_float2(mr-ni,mi+nr);
    }
}

// Stockham store with preloaded twiddles w[r-1] = W^(p*r).
template<int OFFM>
__device__ __forceinline__ void r8_store_tw(float2* Lw, const float2* y, const float2* w)
{
    Lw[0] = y[0];
#pragma unroll
    for (int r = 1; r < 8; ++r)
        Lw[OFFM*r] = make_float2(w[r-1].x*y[r].x - w[r-1].y*y[r].y,
                                 w[r-1].x*y[r].y + w[r-1].y*y[r].x);
}

__global__ __launch_bounds__(TPB, 8) void fourier_ln_kernel(
    const float* __restrict__ x,
    const float* __restrict__ gamma,
    const float* __restrict__ beta,
    float* __restrict__ out)
{
    __shared__ float2 L[2304];    // 2048 logical + pad: phys(i) = i + (i>>3)
    __shared__ float rmem[16];    // cross-wave reduction scratch

    const int t  = threadIdx.x;
    const int t8 = t >> 3;
    const long long row0 = 2LL * (long long)blockIdx.x;
    const float* __restrict__ x0 = x + row0 * CD;
    const float* __restrict__ x1 = x0 + CD;

    // Direct strided-coalesced loads: element t+256r of z = x0 + i*x1.
    float2 z[8], y[8];
#pragma unroll
    for (int r = 0; r < 8; ++r) {
        const int k = t + 256*r;
        z[r] = make_float2(x0[k], x1[k]);
    }
    // Stage-A twiddles (coalesced, L2-hot), issued while x loads are in flight.
    float2 wA[7];
#pragma unroll
    for (int r = 0; r < 7; ++r) wA[r] = g_tw[r*256 + t];

    float2* const Lr = L + (t + t8);   // logical t+256r -> phys base + 288r

    // Stage A: radix-8, S=1 (q=0, p=t). logical 8t+r -> phys 9t+r.
    dft8(z, y);
    r8_store_tw<1>(L + 9*t, y, wA);
    // Stage-B twiddles (8-lane broadcast): issue now, consume after barrier+read.
    float2 wB[7];
#pragma unroll
    for (int r = 0; r < 7; ++r) wB[r] = g_tw[1792 + r*32 + t8];
    __syncthreads();
#pragma unroll
    for (int r = 0; r < 8; ++r) z[r] = Lr[288*r];
    __syncthreads();

    // Stage B: radix-8, S=8 (q=t&7, p=t>>3). logical q+64p+8r -> phys q+72p+9r.
    dft8(z, y);
    r8_store_tw<9>(L + ((t & 7) + 72*t8), y, wB);
    // Stage-C twiddles (wave-uniform p = t>>6).
    float2 wC[7];
#pragma unroll
    for (int r = 0; r < 7; ++r) wC[r] = g_tw[2016 + r*4 + (t >> 6)];
    __syncthreads();
#pragma unroll
    for (int r = 0; r < 8; ++r) z[r] = Lr[288*r];
    __syncthreads();

    // Stage C: radix-8, S=64 (q=t&63, p=t>>6). logical q+512p+64r -> phys q+(q>>3)+576p+72r.
    dft8(z, y);
    {
        const int q = t & 63, p = t >> 6;
        r8_store_tw<72>(L + (q + (q >> 3) + 576*p), y, wC);
    }
    __syncthreads();

    // sigma: final-stage butterfly assignment. Even lane of a pair takes
    // sigma=u (u = t>>1 in [0,128)), odd lane takes 256-u (u==0 -> 128).
    // Partner pairs {sigma, 256-sigma} are lane-adjacent -> shfl_xor(1).
    const int u   = t >> 1;
    const int sig = (t & 1) ? ((u == 0) ? 128 : 256 - u) : u;

    // Stage C -> D read at butterfly sig: logical sig+256r.
    {
        const float2* Lsig = L + (sig + (sig >> 3));
#pragma unroll
        for (int r = 0; r < 8; ++r) z[r] = Lsig[288*r];
    }
    // (no further writes to L: no closing barrier needed)

    // Prefetch gamma/beta (L2-resident) under the stage-D VALU work.
    float gv[8], bv[8];
#pragma unroll
    for (int j = 0; j < 8; ++j) {
        gv[j] = gamma[sig + 256*j];
        bv[j] = beta[sig + 256*j];
    }

    // Stage D: radix-4, S=512, p=0 (twiddle-free), in registers.
    // Z[j] = FFT(row0 + i*row1) at k = sig + 256*j, natural order.
    float2 Z[8];
    {
        float pr=z[0].x+z[4].x, pi=z[0].y+z[4].y, mr=z[0].x-z[4].x, mi=z[0].y-z[4].y;
        float qr=z[2].x+z[6].x, qi=z[2].y+z[6].y, nr=z[2].x-z[6].x, ni=z[2].y-z[6].y;
        Z[0]=make_float2(pr+qr,pi+qi); Z[2]=make_float2(mr+ni,mi-nr);
        Z[4]=make_float2(pr-qr,pi-qi); Z[6]=make_float2(mr-ni,mi+nr);
    }
    {
        float pr=z[1].x+z[5].x, pi=z[1].y+z[5].y, mr=z[1].x-z[5].x, mi=z[1].y-z[5].y;
        float qr=z[3].x+z[7].x, qi=z[3].y+z[7].y, nr=z[3].x-z[7].x, ni=z[3].y-z[7].y;
        Z[1]=make_float2(pr+qr,pi+qi); Z[3]=make_float2(mr+ni,mi-nr);
        Z[5]=make_float2(pr-qr,pi-qi); Z[7]=make_float2(mr-ni,mi+nr);
    }

    // Untangle via lane-pair swap: Z[2048-k] lives at (partner lane, j'=7-j).
    // Specials: t==0 (sig=0) self-partner j'=(8-j)&7; t==1 (sig=128) j'=7-j.
    // Re X0[k] = (ReZ[k]+ReZ[-k])/2, Re X1[k] = (ImZ[k]+ImZ[-k])/2.
    float y0v[8], y1v[8];
    float s0=0.f, ss0=0.f, s1=0.f, ss1=0.f;
#pragma unroll
    for (int j = 0; j < 8; ++j) {
        float vx = __shfl_xor(Z[7-j].x, 1, 64);
        float vy = __shfl_xor(Z[7-j].y, 1, 64);
        const int ja = (8-j) & 7;                        // static per unrolled j
        float ax = (t == 0) ? Z[ja].x : Z[7-j].x;
        float ay = (t == 0) ? Z[ja].y : Z[7-j].y;
        vx = (t < 2) ? ax : vx;
        vy = (t < 2) ? ay : vy;
        float a = 0.5f*(Z[j].x + vx);
        float b = 0.5f*(Z[j].y + vy);
        y0v[j]=a; y1v[j]=b;
        s0+=a; ss0+=a*a; s1+=b; ss1+=b*b;
    }

    // Wave-64 shuffle reduce, then cross-wave partials via rmem; every
    // thread folds the 4 partials itself (no t==0 serialization/barrier).
#pragma unroll
    for (int off = 32; off > 0; off >>= 1) {
        s0  += __shfl_down(s0,  off, 64);
        ss0 += __shfl_down(ss0, off, 64);
        s1  += __shfl_down(s1,  off, 64);
        ss1 += __shfl_down(ss1, off, 64);
    }
    const int wave = t >> 6;
    if ((t & 63) == 0) {
        rmem[4*wave+0]=s0; rmem[4*wave+1]=ss0; rmem[4*wave+2]=s1; rmem[4*wave+3]=ss1;
    }
    __syncthreads();
    float S0=0.f, SS0=0.f, S1=0.f, SS1=0.f;
#pragma unroll
    for (int w = 0; w < 4; ++w) {
        S0+=rmem[4*w+0]; SS0+=rmem[4*w+1]; S1+=rmem[4*w+2]; SS1+=rmem[4*w+3];
    }
    const float inv = 1.0f/(float)CD;
    const float mu0 = S0*inv, mu1 = S1*inv;
    const float r0 = rsqrtf(SS0*inv - mu0*mu0 + 1e-5f);
    const float r1 = rsqrtf(SS1*inv - mu1*mu1 + 1e-5f);

    // Plain stores (NT experiment reverted: it amplified HBM writes +17%).
    float* __restrict__ o0 = out + row0*CD;
    float* __restrict__ o1 = o0 + CD;
#pragma unroll
    for (int j = 0; j < 8; ++j) {
        const int k = sig + 256*j;
        const float rg0 = r0 * gv[j], rg1 = r1 * gv[j];
        o0[k] = (y0v[j] - mu0) * rg0 + bv[j];
        o1[k] = (y1v[j] - mu1) * rg1 + bv[j];
    }
}

extern "C" void kernel_launch(void* const* d_in, const int* in_sizes, int n_in,
                              void* d_out, int out_size, void* d_ws, size_t ws_size,
                              hipStream_t stream) {
    (void)in_sizes; (void)n_in; (void)d_ws; (void)ws_size; (void)out_size;
    const float* x     = (const float*)d_in[0];
    const float* gamma = (const float*)d_in[1];
    const float* beta  = (const float*)d_in[2];
    float* out = (float*)d_out;

    // Twiddle table init (16 KB device-global) — captured in the same graph,
    // negligible cost (8 blocks), keeps the main kernel free of sincos chains.
    twiddle_init_kernel<<<8, TPB, 0, stream>>>();

    const int total_rows = 4 * 4096;           // B * N
    const int blocks = total_rows / 2;         // one block per row pair
    fourier_ln_kernel<<<blocks, TPB, 0, stream>>>(x, gamma, beta, out);
}

// Round 7
// 236.080 us; speedup vs baseline: 1.1003x; 1.0918x over previous
//
#include <hip/hip_runtime.h>
#include <math.h>

// LayerNorm(Re(FFT(x, axis=-1))), x: (B=4, N=4096, C=2048) fp32.
// One 256-thread block per TWO row-pairs (4 rows): zA = x0+i*x1, zB = x2+i*x3.
// Register-resident Stockham FFT per pair: radix-8 stages (S=1,8,64) + final
// radix-4 (S=512, twiddle-free, in registers). The two pairs interleave
// between the SAME barriers (own LDS buffer each): per pair the barrier count
// halves (6 -> 3) and twiddles (inline __sincosf + tree powers -- the round-6
// table experiment cost +21us in barrier vmcnt drains, reverted) plus
// gamma/beta loads are computed once and shared.
// Conjugate-symmetry untangle via __shfl_xor(.,1) (pairs {s,256-s} lane-adjacent).
// Padded LDS phys(i) = i + (i>>3); 2 buffers = 36.9 KB -> 4 blocks/CU.

#define TPB 256
#define CD  2048

__device__ __forceinline__ float2 cadd(float2 a, float2 b){ return make_float2(a.x+b.x, a.y+b.y); }
__device__ __forceinline__ float2 csub(float2 a, float2 b){ return make_float2(a.x-b.x, a.y-b.y); }

// y_r = sum_k z_k * exp(-2*pi*i*k*r/8), natural output order.
__device__ __forceinline__ void dft8(const float2* z, float2* y)
{
    const float C8 = 0.70710678118654752440f;  // sqrt(2)/2
    float2 a0=cadd(z[0],z[4]), a1=cadd(z[1],z[5]), a2=cadd(z[2],z[6]), a3=cadd(z[3],z[7]);
    float2 b0=csub(z[0],z[4]), b1=csub(z[1],z[5]), b2=csub(z[2],z[6]), b3=csub(z[3],z[7]);
    float2 t1=make_float2(C8*(b1.x+b1.y), C8*(b1.y-b1.x));     // b1 * w8^1
    float2 t2=make_float2(b2.y, -b2.x);                        // b2 * w8^2 = -i
    float2 t3=make_float2(C8*(b3.y-b3.x), -C8*(b3.x+b3.y));    // b3 * w8^3
    {   // even outputs = DFT4(a0..a3)
        float pr=a0.x+a2.x, pi=a0.y+a2.y, mr=a0.x-a2.x, mi=a0.y-a2.y;
        float qr=a1.x+a3.x, qi=a1.y+a3.y, nr=a1.x-a3.x, ni=a1.y-a3.y;
        y[0]=make_float2(pr+qr,pi+qi); y[2]=make_float2(mr+ni,mi-nr);
        y[4]=make_float2(pr-qr,pi-qi); y[6]=make_float2(mr-ni,mi+nr);
    }
    {   // odd outputs = DFT4(b0,t1,t2,t3)
        float pr=b0.x+t2.x, pi=b0.y+t2.y, mr=b0.x-t2.x, mi=b0.y-t2.y;
        float qr=t1.x+t3.x, qi=t1.y+t3.y, nr=t1.x-t3.x, ni=t1.y-t3.y;
        y[1]=make_float2(pr+qr,pi+qi); y[3]=make_float2(mr+ni,mi-nr);
        y[5]=make_float2(pr-qr,pi-qi); y[7]=make_float2(mr-ni,mi+nr);
    }
}

// cw[r],sw[r] = cos/sin(th1*r), r=0..7; tree-structured (dep depth 3).
__device__ __forceinline__ void make_tw(float th1, float* cw, float* sw)
{
    float s1, c1;
    __sincosf(th1, &s1, &c1);
    cw[0]=1.f;                       sw[0]=0.f;
    cw[1]=c1;                        sw[1]=s1;
    cw[2]=c1*c1-s1*s1;               sw[2]=2.f*c1*s1;
    cw[4]=cw[2]*cw[2]-sw[2]*sw[2];   sw[4]=2.f*cw[2]*sw[2];
    cw[3]=c1*cw[2]-s1*sw[2];         sw[3]=s1*cw[2]+c1*sw[2];
    cw[5]=c1*cw[4]-s1*sw[4];         sw[5]=s1*cw[4]+c1*sw[4];
    cw[6]=cw[2]*cw[4]-sw[2]*sw[4];   sw[6]=sw[2]*cw[4]+cw[2]*sw[4];
    cw[7]=cw[3]*cw[4]-sw[3]*sw[4];   sw[7]=sw[3]*cw[4]+cw[3]*sw[4];
}

// Stockham store with shared twiddles w_r = (cw[r], sw[r]).
template<int OFFM>
__device__ __forceinline__ void r8_store(float2* Lw, const float2* y,
                                         const float* cw, const float* sw)
{
    Lw[0] = y[0];
#pragma unroll
    for (int r = 1; r < 8; ++r)
        Lw[OFFM*r] = make_float2(cw[r]*y[r].x - sw[r]*y[r].y,
                                 cw[r]*y[r].y + sw[r]*y[r].x);
}

// Final radix-4 (S=512, twiddle-free) + conjugate-symmetry untangle + moments.
// z: stage-C outputs at logical sig+256r. Outputs y0v/y1v at k=sig+256j and
// running sums. Partner Z[2048-k] is one __shfl_xor(.,1) away; specials:
// t==0 (sig=0) self-partner j'=(8-j)&7; t==1 (sig=128) self, j'=7-j.
__device__ __forceinline__ void stageD_untangle(const float2* z, int t,
        float* y0v, float* y1v, float& s0, float& ss0, float& s1, float& ss1)
{
    float2 Z[8];
    {
        float pr=z[0].x+z[4].x, pi=z[0].y+z[4].y, mr=z[0].x-z[4].x, mi=z[0].y-z[4].y;
        float qr=z[2].x+z[6].x, qi=z[2].y+z[6].y, nr=z[2].x-z[6].x, ni=z[2].y-z[6].y;
        Z[0]=make_float2(pr+qr,pi+qi); Z[2]=make_float2(mr+ni,mi-nr);
        Z[4]=make_float2(pr-qr,pi-qi); Z[6]=make_float2(mr-ni,mi+nr);
    }
    {
        float pr=z[1].x+z[5].x, pi=z[1].y+z[5].y, mr=z[1].x-z[5].x, mi=z[1].y-z[5].y;
        float qr=z[3].x+z[7].x, qi=z[3].y+z[7].y, nr=z[3].x-z[7].x, ni=z[3].y-z[7].y;
        Z[1]=make_float2(pr+qr,pi+qi); Z[3]=make_float2(mr+ni,mi-nr);
        Z[5]=make_float2(pr-qr,pi-qi); Z[7]=make_float2(mr-ni,mi+nr);
    }
#pragma unroll
    for (int j = 0; j < 8; ++j) {
        float vx = __shfl_xor(Z[7-j].x, 1, 64);
        float vy = __shfl_xor(Z[7-j].y, 1, 64);
        const int ja = (8-j) & 7;                        // static per unrolled j
        float ax = (t == 0) ? Z[ja].x : Z[7-j].x;
        float ay = (t == 0) ? Z[ja].y : Z[7-j].y;
        vx = (t < 2) ? ax : vx;
        vy = (t < 2) ? ay : vy;
        float a = 0.5f*(Z[j].x + vx);
        float b = 0.5f*(Z[j].y + vy);
        y0v[j]=a; y1v[j]=b;
        s0+=a; ss0+=a*a; s1+=b; ss1+=b*b;
    }
}

__global__ __launch_bounds__(TPB, 4) void fourier_ln_kernel(
    const float* __restrict__ x,
    const float* __restrict__ gamma,
    const float* __restrict__ beta,
    float* __restrict__ out)
{
    __shared__ float2 LA[2304];   // pair A: 2048 logical + pad, phys(i)=i+(i>>3)
    __shared__ float2 LB[2304];   // pair B
    __shared__ float rmem[32];    // cross-wave reduction scratch (8 per wave)

    const int t  = threadIdx.x;
    const int t8 = t >> 3;
    const long long rowa = 4LL * (long long)blockIdx.x;
    const float* __restrict__ xa0 = x + rowa * CD;
    const float* __restrict__ xa1 = xa0 + CD;
    const float* __restrict__ xb0 = xa0 + 2 * CD;
    const float* __restrict__ xb1 = xa0 + 3 * CD;

    // Strided-coalesced loads for both pairs (32 loads in flight).
    float2 za[8], zb[8], y[8];
#pragma unroll
    for (int r = 0; r < 8; ++r) {
        const int k = t + 256*r;
        za[r] = make_float2(xa0[k], xa1[k]);
    }
#pragma unroll
    for (int r = 0; r < 8; ++r) {
        const int k = t + 256*r;
        zb[r] = make_float2(xb0[k], xb1[k]);
    }

    float2* const LAr = LA + (t + t8);   // logical t+256r -> phys base + 288r
    float2* const LBr = LB + (t + t8);

    float cw[8], sw[8];

    // Stage A: radix-8, S=1 (p=t). logical 8t+r -> phys 9t+r.
    make_tw(-3.06796157577128245943e-3f * (float)t, cw, sw);   // -2pi/2048 * t
    dft8(za, y);  r8_store<1>(LA + 9*t, y, cw, sw);
    dft8(zb, y);  r8_store<1>(LB + 9*t, y, cw, sw);
    __syncthreads();
#pragma unroll
    for (int r = 0; r < 8; ++r) za[r] = LAr[288*r];
#pragma unroll
    for (int r = 0; r < 8; ++r) zb[r] = LBr[288*r];
    __syncthreads();

    // Stage B: radix-8, S=8 (q=t&7, p=t>>3). logical q+64p+8r -> phys q+72p+9r.
    make_tw(-2.45436926061702596755e-2f * (float)t8, cw, sw);  // -2pi/256 * p
    dft8(za, y);  r8_store<9>(LA + ((t & 7) + 72*t8), y, cw, sw);
    dft8(zb, y);  r8_store<9>(LB + ((t & 7) + 72*t8), y, cw, sw);
    __syncthreads();
#pragma unroll
    for (int r = 0; r < 8; ++r) za[r] = LAr[288*r];
#pragma unroll
    for (int r = 0; r < 8; ++r) zb[r] = LBr[288*r];
    __syncthreads();

    // Stage C: radix-8, S=64 (q=t&63, p=t>>6). logical q+512p+64r -> phys q+(q>>3)+576p+72r.
    {
        const int q = t & 63, p = t >> 6;
        make_tw(-1.96349540849362077404e-1f * (float)p, cw, sw);  // -2pi/32 * p
        const int off = q + (q >> 3) + 576*p;
        dft8(za, y);  r8_store<72>(LA + off, y, cw, sw);
        dft8(zb, y);  r8_store<72>(LB + off, y, cw, sw);
    }
    __syncthreads();

    // sigma: even lane of a pair takes sig=u (u=t>>1), odd takes 256-u (u==0 -> 128).
    const int u   = t >> 1;
    const int sig = (t & 1) ? ((u == 0) ? 128 : 256 - u) : u;

    // Stage C -> D reads at butterfly sig (no further LA/LB writes: no barrier).
    {
        const int soff = sig + (sig >> 3);
        const float2* LAs = LA + soff;
        const float2* LBs = LB + soff;
#pragma unroll
        for (int r = 0; r < 8; ++r) za[r] = LAs[288*r];
#pragma unroll
        for (int r = 0; r < 8; ++r) zb[r] = LBs[288*r];
    }

    // gamma/beta: shared across all 4 rows, prefetched under stage-D VALU.
    float gv[8], bv[8];
#pragma unroll
    for (int j = 0; j < 8; ++j) {
        gv[j] = gamma[sig + 256*j];
        bv[j] = beta[sig + 256*j];
    }

    // Stage D + untangle + moments, per pair.
    float y0a[8], y1a[8], y0b[8], y1b[8];
    float sa0=0.f, ssa0=0.f, sa1=0.f, ssa1=0.f;
    float sb0=0.f, ssb0=0.f, sb1=0.f, ssb1=0.f;
    stageD_untangle(za, t, y0a, y1a, sa0, ssa0, sa1, ssa1);
    stageD_untangle(zb, t, y0b, y1b, sb0, ssb0, sb1, ssb1);

    // Wave-64 shuffle reduce (8 values), cross-wave via rmem; all threads fold.
#pragma unroll
    for (int off = 32; off > 0; off >>= 1) {
        sa0 += __shfl_down(sa0, off, 64);  ssa0 += __shfl_down(ssa0, off, 64);
        sa1 += __shfl_down(sa1, off, 64);  ssa1 += __shfl_down(ssa1, off, 64);
        sb0 += __shfl_down(sb0, off, 64);  ssb0 += __shfl_down(ssb0, off, 64);
        sb1 += __shfl_down(sb1, off, 64);  ssb1 += __shfl_down(ssb1, off, 64);
    }
    const int wave = t >> 6;
    if ((t & 63) == 0) {
        rmem[8*wave+0]=sa0; rmem[8*wave+1]=ssa0; rmem[8*wave+2]=sa1; rmem[8*wave+3]=ssa1;
        rmem[8*wave+4]=sb0; rmem[8*wave+5]=ssb0; rmem[8*wave+6]=sb1; rmem[8*wave+7]=ssb1;
    }
    __syncthreads();
    float SA0=0.f, SSA0=0.f, SA1=0.f, SSA1=0.f;
    float SB0=0.f, SSB0=0.f, SB1=0.f, SSB1=0.f;
#pragma unroll
    for (int w = 0; w < 4; ++w) {
        SA0+=rmem[8*w+0]; SSA0+=rmem[8*w+1]; SA1+=rmem[8*w+2]; SSA1+=rmem[8*w+3];
        SB0+=rmem[8*w+4]; SSB0+=rmem[8*w+5]; SB1+=rmem[8*w+6]; SSB1+=rmem[8*w+7];
    }
    const float inv = 1.0f/(float)CD;
    const float mua0 = SA0*inv, mua1 = SA1*inv, mub0 = SB0*inv, mub1 = SB1*inv;
    const float ra0 = rsqrtf(SSA0*inv - mua0*mua0 + 1e-5f);
    const float ra1 = rsqrtf(SSA1*inv - mua1*mua1 + 1e-5f);
    const float rb0 = rsqrtf(SSB0*inv - mub0*mub0 + 1e-5f);
    const float rb1 = rsqrtf(SSB1*inv - mub1*mub1 + 1e-5f);

    float* __restrict__ oa0 = out + rowa*CD;
    float* __restrict__ oa1 = oa0 + CD;
    float* __restrict__ ob0 = oa0 + 2*CD;
    float* __restrict__ ob1 = oa0 + 3*CD;
#pragma unroll
    for (int j = 0; j < 8; ++j) {
        const int k = sig + 256*j;
        const float g = gv[j], be = bv[j];
        oa0[k] = (y0a[j] - mua0) * ra0 * g + be;
        oa1[k] = (y1a[j] - mua1) * ra1 * g + be;
        ob0[k] = (y0b[j] - mub0) * rb0 * g + be;
        ob1[k] = (y1b[j] - mub1) * rb1 * g + be;
    }
}

extern "C" void kernel_launch(void* const* d_in, const int* in_sizes, int n_in,
                              void* d_out, int out_size, void* d_ws, size_t ws_size,
                              hipStream_t stream) {
    (void)in_sizes; (void)n_in; (void)d_ws; (void)ws_size; (void)out_size;
    const float* x     = (const float*)d_in[0];
    const float* gamma = (const float*)d_in[1];
    const float* beta  = (const float*)d_in[2];
    float* out = (float*)d_out;

    const int total_rows = 4 * 4096;           // B * N
    const int blocks = total_rows / 4;         // one block per TWO row-pairs
    fourier_ln_kernel<<<blocks, TPB, 0, stream>>>(x, gamma, beta, out);
}

// Round 8
// 231.532 us; speedup vs baseline: 1.1220x; 1.0196x over previous
//
#include <hip/hip_runtime.h>
#include <math.h>

// LayerNorm(Re(FFT(x, axis=-1))), x: (B=4, N=4096, C=2048) fp32.
// One 256-thread block per PAIR of rows: z = x_even + i*x_odd.
// Register-resident Stockham FFT: radix-8 stages (S=1,8,64) + final radix-4
// (S=512, twiddle-free, in registers). Inline __sincosf + tree powers
// (twiddle-table experiment: +21us barrier-drain, reverted; ILP-2: -39% occ,
// reverted). Conjugate untangle via __shfl_xor(.,1) (pairs {s,256-s}
// lane-adjacent). NEW: epilogue repartitioned through LDS -- each thread
// writes its raw (y0,y1) back to the L slots it alone read (race-free, no
// extra barrier), then reads contiguous k=4t..4t+3 / 1024+4t..4t+3 and emits
// fully-coalesced float4 stores + float4 gamma/beta loads, replacing the
// sig-scattered 20 dword VMEM ops/thread of the old epilogue.
// Padded LDS phys(i) = i + (i>>3): 18.4 KB/block -> 8 blocks/CU.

#define TPB 256
#define CD  2048

__device__ __forceinline__ float2 cadd(float2 a, float2 b){ return make_float2(a.x+b.x, a.y+b.y); }
__device__ __forceinline__ float2 csub(float2 a, float2 b){ return make_float2(a.x-b.x, a.y-b.y); }

// y_r = sum_k z_k * exp(-2*pi*i*k*r/8), natural output order.
__device__ __forceinline__ void dft8(const float2* z, float2* y)
{
    const float C8 = 0.70710678118654752440f;  // sqrt(2)/2
    float2 a0=cadd(z[0],z[4]), a1=cadd(z[1],z[5]), a2=cadd(z[2],z[6]), a3=cadd(z[3],z[7]);
    float2 b0=csub(z[0],z[4]), b1=csub(z[1],z[5]), b2=csub(z[2],z[6]), b3=csub(z[3],z[7]);
    float2 t1=make_float2(C8*(b1.x+b1.y), C8*(b1.y-b1.x));     // b1 * w8^1
    float2 t2=make_float2(b2.y, -b2.x);                        // b2 * w8^2 = -i
    float2 t3=make_float2(C8*(b3.y-b3.x), -C8*(b3.x+b3.y));    // b3 * w8^3
    {   // even outputs = DFT4(a0..a3)
        float pr=a0.x+a2.x, pi=a0.y+a2.y, mr=a0.x-a2.x, mi=a0.y-a2.y;
        float qr=a1.x+a3.x, qi=a1.y+a3.y, nr=a1.x-a3.x, ni=a1.y-a3.y;
        y[0]=make_float2(pr+qr,pi+qi); y[2]=make_float2(mr+ni,mi-nr);
        y[4]=make_float2(pr-qr,pi-qi); y[6]=make_float2(mr-ni,mi+nr);
    }
    {   // odd outputs = DFT4(b0,t1,t2,t3)
        float pr=b0.x+t2.x, pi=b0.y+t2.y, mr=b0.x-t2.x, mi=b0.y-t2.y;
        float qr=t1.x+t3.x, qi=t1.y+t3.y, nr=t1.x-t3.x, ni=t1.y-t3.y;
        y[1]=make_float2(pr+qr,pi+qi); y[3]=make_float2(mr+ni,mi-nr);
        y[5]=make_float2(pr-qr,pi-qi); y[7]=make_float2(mr-ni,mi+nr);
    }
}

// cw[r],sw[r] = cos/sin(th1*r), r=0..7; tree-structured (dep depth 3).
__device__ __forceinline__ void make_tw(float th1, float* cw, float* sw)
{
    float s1, c1;
    __sincosf(th1, &s1, &c1);
    cw[0]=1.f;                       sw[0]=0.f;
    cw[1]=c1;                        sw[1]=s1;
    cw[2]=c1*c1-s1*s1;               sw[2]=2.f*c1*s1;
    cw[4]=cw[2]*cw[2]-sw[2]*sw[2];   sw[4]=2.f*cw[2]*sw[2];
    cw[3]=c1*cw[2]-s1*sw[2];         sw[3]=s1*cw[2]+c1*sw[2];
    cw[5]=c1*cw[4]-s1*sw[4];         sw[5]=s1*cw[4]+c1*sw[4];
    cw[6]=cw[2]*cw[4]-sw[2]*sw[4];   sw[6]=sw[2]*cw[4]+cw[2]*sw[4];
    cw[7]=cw[3]*cw[4]-sw[3]*sw[4];   sw[7]=sw[3]*cw[4]+cw[3]*sw[4];
}

// Stockham store with twiddles w_r = (cw[r], sw[r]).
template<int OFFM>
__device__ __forceinline__ void r8_store(float2* Lw, const float2* y,
                                         const float* cw, const float* sw)
{
    Lw[0] = y[0];
#pragma unroll
    for (int r = 1; r < 8; ++r)
        Lw[OFFM*r] = make_float2(cw[r]*y[r].x - sw[r]*y[r].y,
                                 cw[r]*y[r].y + sw[r]*y[r].x);
}

__global__ __launch_bounds__(TPB, 8) void fourier_ln_kernel(
    const float* __restrict__ x,
    const float* __restrict__ gamma,
    const float* __restrict__ beta,
    float* __restrict__ out)
{
    __shared__ float2 L[2304];    // 2048 logical + pad: phys(i) = i + (i>>3)
    __shared__ float rmem[16];    // cross-wave reduction scratch

    const int t  = threadIdx.x;
    const int t8 = t >> 3;
    const long long row0 = 2LL * (long long)blockIdx.x;
    const float* __restrict__ x0 = x + row0 * CD;
    const float* __restrict__ x1 = x0 + CD;

    // Strided-coalesced loads: element t+256r of z = x0 + i*x1.
    float2 z[8], y[8];
#pragma unroll
    for (int r = 0; r < 8; ++r) {
        const int k = t + 256*r;
        z[r] = make_float2(x0[k], x1[k]);
    }

    float2* const Lr = L + (t + t8);   // logical t+256r -> phys base + 288r
    float cw[8], sw[8];

    // Stage A: radix-8, S=1 (p=t). logical 8t+r -> phys 9t+r.
    make_tw(-3.06796157577128245943e-3f * (float)t, cw, sw);   // -2pi/2048 * t
    dft8(z, y);
    r8_store<1>(L + 9*t, y, cw, sw);
    __syncthreads();
#pragma unroll
    for (int r = 0; r < 8; ++r) z[r] = Lr[288*r];
    __syncthreads();

    // Stage B: radix-8, S=8 (q=t&7, p=t>>3). logical q+64p+8r -> phys q+72p+9r.
    make_tw(-2.45436926061702596755e-2f * (float)t8, cw, sw);  // -2pi/256 * p
    dft8(z, y);
    r8_store<9>(L + ((t & 7) + 72*t8), y, cw, sw);
    __syncthreads();
#pragma unroll
    for (int r = 0; r < 8; ++r) z[r] = Lr[288*r];
    __syncthreads();

    // Stage C: radix-8, S=64 (q=t&63, p=t>>6). logical q+512p+64r -> phys q+(q>>3)+576p+72r.
    dft8(z, y);
    {
        const int q = t & 63, p = t >> 6;
        make_tw(-1.96349540849362077404e-1f * (float)p, cw, sw);  // -2pi/32 * p
        r8_store<72>(L + (q + (q >> 3) + 576*p), y, cw, sw);
    }
    __syncthreads();

    // sigma: even lane of a pair takes sig=u (u=t>>1), odd takes 256-u (u==0 -> 128).
    // Partner pairs {sig, 256-sig} are lane-adjacent -> shfl_xor(1).
    const int u   = t >> 1;
    const int sig = (t & 1) ? ((u == 0) ? 128 : 256 - u) : u;

    // Stage C -> D read at butterfly sig: logical sig+256r (unique per thread).
    float2* const Lsig = L + (sig + (sig >> 3));
#pragma unroll
    for (int r = 0; r < 8; ++r) z[r] = Lsig[288*r];

    // Stage D: radix-4, S=512, p=0 (twiddle-free), in registers.
    // Z[j] = FFT(row0 + i*row1) at k = sig + 256*j, natural order.
    float2 Z[8];
    {
        float pr=z[0].x+z[4].x, pi=z[0].y+z[4].y, mr=z[0].x-z[4].x, mi=z[0].y-z[4].y;
        float qr=z[2].x+z[6].x, qi=z[2].y+z[6].y, nr=z[2].x-z[6].x, ni=z[2].y-z[6].y;
        Z[0]=make_float2(pr+qr,pi+qi); Z[2]=make_float2(mr+ni,mi-nr);
        Z[4]=make_float2(pr-qr,pi-qi); Z[6]=make_float2(mr-ni,mi+nr);
    }
    {
        float pr=z[1].x+z[5].x, pi=z[1].y+z[5].y, mr=z[1].x-z[5].x, mi=z[1].y-z[5].y;
        float qr=z[3].x+z[7].x, qi=z[3].y+z[7].y, nr=z[3].x-z[7].x, ni=z[3].y-z[7].y;
        Z[1]=make_float2(pr+qr,pi+qi); Z[3]=make_float2(mr+ni,mi-nr);
        Z[5]=make_float2(pr-qr,pi-qi); Z[7]=make_float2(mr-ni,mi+nr);
    }

    // Untangle via lane-pair swap: Z[2048-k] lives at (partner lane, j'=7-j).
    // Specials: t==0 (sig=0) self-partner j'=(8-j)&7; t==1 (sig=128) j'=7-j.
    // Re X0[k] = (ReZ[k]+ReZ[-k])/2, Re X1[k] = (ImZ[k]+ImZ[-k])/2.
    // Write raw (y0,y1) back into the SAME L slots this thread alone read:
    // race-free; the reduction barrier below publishes them for repartition.
    float s0=0.f, ss0=0.f, s1=0.f, ss1=0.f;
#pragma unroll
    for (int j = 0; j < 8; ++j) {
        float vx = __shfl_xor(Z[7-j].x, 1, 64);
        float vy = __shfl_xor(Z[7-j].y, 1, 64);
        const int ja = (8-j) & 7;                        // static per unrolled j
        float ax = (t == 0) ? Z[ja].x : Z[7-j].x;
        float ay = (t == 0) ? Z[ja].y : Z[7-j].y;
        vx = (t < 2) ? ax : vx;
        vy = (t < 2) ? ay : vy;
        float a = 0.5f*(Z[j].x + vx);
        float b = 0.5f*(Z[j].y + vy);
        Lsig[288*j] = make_float2(a, b);
        s0+=a; ss0+=a*a; s1+=b; ss1+=b*b;
    }

    // Wave-64 shuffle reduce, then cross-wave partials via rmem; every
    // thread folds the 4 partials itself.
#pragma unroll
    for (int off = 32; off > 0; off >>= 1) {
        s0  += __shfl_down(s0,  off, 64);
        ss0 += __shfl_down(ss0, off, 64);
        s1  += __shfl_down(s1,  off, 64);
        ss1 += __shfl_down(ss1, off, 64);
    }
    const int wave = t >> 6;
    if ((t & 63) == 0) {
        rmem[4*wave+0]=s0; rmem[4*wave+1]=ss0; rmem[4*wave+2]=s1; rmem[4*wave+3]=ss1;
    }
    __syncthreads();   // publishes rmem partials AND the raw y-values in L

    // Coalesced gamma/beta (float4) at float4-index t, t+256; issued first so
    // the L2 latency hides under the rmem fold + LDS reads below.
    const float4 g0 = ((const float4*)gamma)[t];
    const float4 b0 = ((const float4*)beta )[t];
    const float4 g1 = ((const float4*)gamma)[t + 256];
    const float4 b1 = ((const float4*)beta )[t + 256];

    float S0=0.f, SS0=0.f, S1=0.f, SS1=0.f;
#pragma unroll
    for (int w = 0; w < 4; ++w) {
        S0+=rmem[4*w+0]; SS0+=rmem[4*w+1]; S1+=rmem[4*w+2]; SS1+=rmem[4*w+3];
    }
    const float inv = 1.0f/(float)CD;
    const float mu0 = S0*inv, mu1 = S1*inv;
    const float r0 = rsqrtf(SS0*inv - mu0*mu0 + 1e-5f);
    const float r1 = rsqrtf(SS1*inv - mu1*mu1 + 1e-5f);

    // Repartitioned epilogue: thread t handles CONTIGUOUS k in [4t,4t+4) and
    // [1024+4t, 1024+4t+4). phys(4t+1024h+c) = 4t+(t>>1) + 1152h + c.
    const float2* const Ls = L + (4*t + (t >> 1));
    float4* __restrict__ o0 = (float4*)(out + row0*CD);
    float4* __restrict__ o1 = (float4*)(out + (row0+1)*CD);
#pragma unroll
    for (int h = 0; h < 2; ++h) {
        float2 p0 = Ls[1152*h + 0];
        float2 p1 = Ls[1152*h + 1];
        float2 p2 = Ls[1152*h + 2];
        float2 p3 = Ls[1152*h + 3];
        const float4 g = h ? g1 : g0;
        const float4 be = h ? b1 : b0;
        float4 v0, v1;
        v0.x=(p0.x-mu0)*r0*g.x+be.x; v1.x=(p0.y-mu1)*r1*g.x+be.x;
        v0.y=(p1.x-mu0)*r0*g.y+be.y; v1.y=(p1.y-mu1)*r1*g.y+be.y;
        v0.z=(p2.x-mu0)*r0*g.z+be.z; v1.z=(p2.y-mu1)*r1*g.z+be.z;
        v0.w=(p3.x-mu0)*r0*g.w+be.w; v1.w=(p3.y-mu1)*r1*g.w+be.w;
        o0[t + 256*h] = v0;
        o1[t + 256*h] = v1;
    }
}

extern "C" void kernel_launch(void* const* d_in, const int* in_sizes, int n_in,
                              void* d_out, int out_size, void* d_ws, size_t ws_size,
                              hipStream_t stream) {
    (void)in_sizes; (void)n_in; (void)d_ws; (void)ws_size; (void)out_size;
    const float* x     = (const float*)d_in[0];
    const float* gamma = (const float*)d_in[1];
    const float* beta  = (const float*)d_in[2];
    float* out = (float*)d_out;

    const int total_rows = 4 * 4096;           // B * N
    const int blocks = total_rows / 2;         // one block per row pair
    fourier_ln_kernel<<<blocks, TPB, 0, stream>>>(x, gamma, beta, out);
}